// Round 7
// baseline (3594.920 us; speedup 1.0000x reference)
//
#include <hip/hip_runtime.h>
#include <float.h>

#define NEMB 1024
#define EDIM 256
#define BM   128    // rows per block (z tile); 2 rows per lane
#define HW   4096   // 64*64
#define NT   1024   // 16 waves
#define NW   (NT / 64)
#define NB   8
#define ZQ_ELEMS 33554432   // 32*256*4096

// numpy FLOAT_pairwise_sum of squares, n=256: two 128-blocks, 8 accumulators
// r[j] += a[8i+j], tree-combine ((r0+r1)+(r2+r3))+((r4+r5)+(r6+r7)), then
// blk0+blk1. Squares rounded separately (contract off).
template <typename F>
__device__ __forceinline__ float np_sumsq_256(F get) {
#pragma clang fp contract(off)
    float blk[2];
#pragma unroll
    for (int h = 0; h < 2; ++h) {
        const int base = h * 128;
        float r[8];
#pragma unroll
        for (int j = 0; j < 8; ++j) {
            float v = get(base + j);
            r[j] = v * v;
        }
        for (int i = 8; i < 128; i += 8) {
#pragma unroll
            for (int j = 0; j < 8; ++j) {
                float v = get(base + i + j);
                float p = v * v;
                r[j] = r[j] + p;
            }
        }
        blk[h] = ((r[0] + r[1]) + (r[2] + r[3])) + ((r[4] + r[5]) + (r[6] + r[7]));
    }
    return blk[0] + blk[1];
}

__global__ __launch_bounds__(256) void esq_kernel(const float* __restrict__ emb,
                                                  float* __restrict__ esq) {
    int n = blockIdx.x * 256 + threadIdx.x;
    const float* e = emb + (size_t)n * EDIM;
    esq[n] = np_sumsq_256([&](int k) { return e[k]; });
}

// z tile, PAIR-INTERLEAVED over 128 rows: z(k,row) at word
// (k>>1)*256 + 2*row + (k&1). Lane r owns rows r and r+64; each ds_read_b64
// covers dwords {2r,2r+1} over a 128-dword segment -> conflict-free.
//
// ROUND-7 CHANGE (vector-path emb): rounds 0-6 all fed emb through the
// SCALAR pipe (s_load -> SGPR). Root-cause model: SGPR file (~90 data regs)
// can't hold enough emb in flight, so the compiler (a) copies s_load
// results to VGPRs (~1 v_mov per 2 FMAs = the ~26% non-FMA VALU in R4) and
// (b) drains lgkmcnt(0) per batch, which also kills in-flight ds_reads
// (SMEM returns OOO). Fix: an opaque zero (inline-asm v_mov) added to the
// emb pointer makes er addresses formally divergent -> compiler emits
// global_load_dwordx4 (uniform addr = one coalesced line request,
// broadcast return, L1/L2-resident stream). emb now lands directly in
// VGPRs with counted vmcnt pipelining; lgkm carries ONLY z ds_reads.
// Everything else is byte-identical to R4 (1132 us) for a clean A/B.
__global__ __launch_bounds__(NT, 4) void vq_kernel(const float* __restrict__ z,
                                                   const float* __restrict__ emb,
                                                   const float* __restrict__ esq,
                                                   float* __restrict__ out) {
    __shared__ float zl[BM * EDIM];   // 128 KiB -> 1 block/CU, 16 waves/CU

    const int t   = threadIdx.x;
    const int blk = blockIdx.x;           // 1024 blocks: 32 per batch image
    const int b   = blk >> 5;
    const int hw0 = (blk & 31) * BM;
    const float* zbase = z + (size_t)b * EDIM * HW;

    // ---- stage z tile: 8192 float4, 8 per thread, coalesced along hw ----
#pragma unroll
    for (int pass = 0; pass < 8; ++pass) {
        int f4 = pass * NT + t;
        int r4 = (f4 & 31) * 4;
        int k  = f4 >> 5;
        float4 v = *(const float4*)(zbase + (size_t)k * HW + hw0 + r4);
        int w = (k >> 1) * 256 + 2 * r4 + (k & 1);
        zl[w + 0] = v.x;
        zl[w + 2] = v.y;
        zl[w + 4] = v.z;
        zl[w + 6] = v.w;
    }
    __syncthreads();

    const int r = t & 63;                 // lane id; owns rows r and r+64
    const float* zr = zl + 2 * r;
    // z_sq with exact numpy pairwise semantics (redundant per wave; cheap)
    const float zsq0 = np_sumsq_256([&](int k) { return zr[(k >> 1) * 256 + (k & 1)]; });
    const float zsq1 = np_sumsq_256([&](int k) { return zr[(k >> 1) * 256 + 128 + (k & 1)]; });

    // wave id -> 64-codeword quota (uniform index math stays scalar; the
    // LOAD path below is forced vector via an opaque divergent zero)
    const int q = __builtin_amdgcn_readfirstlane(t >> 6);

    // Opaque zero in a VGPR: compiler cannot fold it or prove uniformity,
    // so emb addresses derived from embv are divergent -> global_load.
    int lzero;
    asm("v_mov_b32 %0, 0" : "=v"(lzero));
    const float* embv = emb + lzero;

    float best0 = FLT_MAX, best1 = FLT_MAX;
    int   bidx0 = 0,       bidx1 = 0;

#pragma unroll 1
    for (int g = 0; g < 8; ++g) {
        const int n0 = q * 64 + g * NB;
        float acc0[NB], acc1[NB];
#pragma unroll
        for (int j = 0; j < NB; ++j) { acc0[j] = 0.f; acc1[j] = 0.f; }

        // 8-k register chunks of z (both rows), double-buffered
        float2 zA[8], zB[8];   // [0..3] row r, [4..7] row r+64
        auto ldz = [&](float2* dst, int kbase) {
            const int m0 = kbase >> 1;
#pragma unroll
            for (int u = 0; u < 4; ++u) {
                dst[u]     = *(const float2*)(zr + (m0 + u) * 256);
                dst[4 + u] = *(const float2*)(zr + (m0 + u) * 256 + 128);
            }
        };
        // e_z: strictly sequential fp32 FMA over k per codeword per row
        // (chunk-ascending, pair-ascending, .x before .y) — bit-identical
        // numpy microkernel order. er chunk = 32 B -> 2 global_load_dwordx4
        // per j (uniform addr, broadcast).
        auto fma8 = [&](const float2* zc, int kbase) {
#pragma unroll
            for (int j = 0; j < NB; ++j) {
                const float* er = embv + (size_t)(n0 + j) * EDIM + kbase;
                float a0 = acc0[j], a1 = acc1[j];
#pragma unroll
                for (int u = 0; u < 4; ++u) {
                    a0 = fmaf(zc[u].x, er[2 * u + 0], a0);
                    a0 = fmaf(zc[u].y, er[2 * u + 1], a0);
                }
#pragma unroll
                for (int u = 0; u < 4; ++u) {
                    a1 = fmaf(zc[4 + u].x, er[2 * u + 0], a1);
                    a1 = fmaf(zc[4 + u].y, er[2 * u + 1], a1);
                }
                acc0[j] = a0; acc1[j] = a1;
            }
        };

        ldz(zA, 0);
        for (int k = 0; k < EDIM; k += 16) {
            ldz(zB, k + 8);
            fma8(zA, k);
            if (k + 16 < EDIM) ldz(zA, k + 16);
            fma8(zB, k + 8);
        }

#pragma unroll
        for (int j = 0; j < NB; ++j) {
            // numpy: dist = RN( RN(zsq+esq) - 2*ez ); 2*ez exact -> fma form
            // is bit-identical.
            float es = esq[n0 + j];
            float t1 = zsq0 + es;
            float d  = fmaf(-2.f, acc0[j], t1);
            if (d < best0) { best0 = d; bidx0 = n0 + j; }   // strict <
            float t2 = zsq1 + es;
            float d2 = fmaf(-2.f, acc1[j], t2);
            if (d2 < best1) { best1 = d2; bidx1 = n0 + j; }
        }
    }

    // ---- cross-wave (min,idx) reduction, reusing zl ----
    __syncthreads();                        // all zl reads done
    float* rv   = zl;                       // [NW*BM] best value
    int*   ri   = (int*)(zl + NW * BM);     // [NW*BM] best idx
    int*   ifin = (int*)(zl + 2 * NW * BM); // [BM]    final idx per row
    rv[q * BM + r]      = best0;
    rv[q * BM + r + 64] = best1;
    ri[q * BM + r]      = bidx0;
    ri[q * BM + r + 64] = bidx1;
    __syncthreads();
    if (t < BM) {
        float bv = rv[t];
        int   bi = ri[t];
#pragma unroll
        for (int w = 1; w < NW; ++w) {
            float v = rv[w * BM + t];
            int   i = ri[w * BM + t];
            // waves cover ascending idx ranges; strict < keeps lowest idx
            if (v < bv) { bv = v; bi = i; }
        }
        ifin[t] = bi;
        out[(size_t)ZQ_ELEMS + (size_t)blk * BM + t] = (float)bi;  // idx as float
    }
    __syncthreads();

    // ---- z_q[b][c][hw] = emb[idx[hw]][c], coalesced float4 along hw ----
    float* zq = out + (size_t)b * EDIM * HW;
#pragma unroll
    for (int pass = 0; pass < 8; ++pass) {
        int f4 = pass * NT + t;
        int r4 = (f4 & 31) * 4;
        int c  = f4 >> 5;
        float4 v;
        v.x = emb[(size_t)ifin[r4 + 0] * EDIM + c];
        v.y = emb[(size_t)ifin[r4 + 1] * EDIM + c];
        v.z = emb[(size_t)ifin[r4 + 2] * EDIM + c];
        v.w = emb[(size_t)ifin[r4 + 3] * EDIM + c];
        *(float4*)(zq + (size_t)c * HW + hw0 + r4) = v;
    }
}

extern "C" void kernel_launch(void* const* d_in, const int* in_sizes, int n_in,
                              void* d_out, int out_size, void* d_ws, size_t ws_size,
                              hipStream_t stream) {
    const float* z   = (const float*)d_in[0];   // [32,256,64,64]
    const float* emb = (const float*)d_in[1];   // [1024,256]
    float* out = (float*)d_out;                 // 33554432 z_q + 131072 idx (as float)
    float* esq = (float*)d_ws;                  // 1024 floats scratch

    esq_kernel<<<NEMB / 256, 256, 0, stream>>>(emb, esq);
    vq_kernel<<<131072 / BM, NT, 0, stream>>>(z, emb, esq, out);
}